// Round 14
// baseline (102.217 us; speedup 1.0000x reference)
//
#include <hip/hip_runtime.h>
#include <math.h>

// Problem geometry
#define MTOT  16384      // B*L
#define DM    1024
#define HIDN  128
#define HNB   256
#define NBAT  4
#define CLK   32         // rows per k_mega block == scan chunk
#define NBLK  512        // MTOT/CLK -> exactly 2 blocks/CU (all co-resident)
#define CPB   128        // chunks per batch (4096/32)

typedef _Float16 v8h __attribute__((ext_vector_type(8)));
typedef float    v4f __attribute__((ext_vector_type(4)));
#define MFMA16(a,b,c) __builtin_amdgcn_mfma_f32_16x16x32_f16((a),(b),(c),0,0,0)

// FRAGMENT-ORDERED weight blobs (d_ws when big enough, else out1 region):
//  W1: 32 k-tiles x 16384 B. Tile: h-frags [np 0..3][fi 0..1][64 lanes x 16B]
//      then l-frags at +8192. Entry lane l: col=32np+16fi+(l&15),
//      k = kt*32 + (l>>4)*8 + e.
//  W2 @524288: 4 k-tiles x 32768 B: h [cg 0..15][64 x 16B], l at +16384.
#define W1TILE  16384
#define W2BASE  524288
#define W2TILE  32768
#define BLOB_BYTES 655360

// k_mega LDS map (65536 B -> 2 blocks/CU):
//  GEMM1: raw A fp32 ring 4 x 4096 @0 ; W1 tri-buffer 3 x 16384 @16384
//  H (post-GEMM1): Hh 8KB @0 | Hl 8KB @8192     (raw dead)
//  Z (post-GEMM2): [32][260] f32 @16384 (33280) (W1 dead)
#define RAWOFF 0
#define W1OFF  16384
#define HHOFF  0
#define HLOFF  8192
#define ZOFF   16384
#define SMEMSZ 65536

#define VMCNT_(N) asm volatile("s_waitcnt vmcnt(" #N ")" ::: "memory")
#define VMCNT(N) VMCNT_(N)
#define BARRIER() do { asm volatile("s_waitcnt lgkmcnt(0)" ::: "memory"); \
                       __builtin_amdgcn_s_barrier(); } while (0)

typedef const __attribute__((address_space(1))) void* gas1_t;
typedef __attribute__((address_space(3))) void* las3_t;

__device__ __forceinline__ void gld16(const void* g, void* l) {
    __builtin_amdgcn_global_load_lds((gas1_t)g, (las3_t)l, 16, 0, 0);
}

// ---------------------------------------------------------------------------
// K0: weights -> fp16-split fragment-ordered blobs; zero lookback flags.
//     Xh = fp16(x); Xl = fp16((x - Xh) * 4096)
// ---------------------------------------------------------------------------
__global__ __launch_bounds__(256) void k_prep(
    const float* __restrict__ W1,   // [1024][128]
    const float* __restrict__ W2,   // [128][256]
    char* __restrict__ blobs,
    int* flags)                     // null in fallback mode
{
    __shared__ float lds[32][260];
    const int t = threadIdx.x, blk = blockIdx.x;
    if (flags && blk < 2)
        __hip_atomic_store(&flags[blk * 256 + t], 0, __ATOMIC_RELAXED,
                           __HIP_MEMORY_SCOPE_AGENT);
    if (blk < 32) {
        const int k0 = blk * 32;
        #pragma unroll
        for (int i = 0; i < 4; ++i) {
            int j = t + i * 256;
            int k = j >> 5, n4 = (j & 31) << 2;
            *(float4*)&lds[k][n4] = *(const float4*)&W1[(size_t)(k0 + k) * HIDN + n4];
        }
        __syncthreads();
        const int fl = t & 63, np = t >> 6;
        const int kb = (fl >> 4) * 8;
        #pragma unroll
        for (int fi = 0; fi < 2; ++fi) {
            const int col = 32 * np + 16 * fi + (fl & 15);
            union { _Float16 h[8]; int4 v; } H, L;
            #pragma unroll
            for (int e = 0; e < 8; ++e) {
                float v = lds[kb + e][col];
                _Float16 hh = (_Float16)v;
                H.h[e] = hh;
                L.h[e] = (_Float16)((v - (float)hh) * 4096.f);
            }
            char* d = blobs + blk * W1TILE + np * 2048 + fi * 1024 + fl * 16;
            *(int4*)d = H.v;
            *(int4*)(d + 8192) = L.v;
        }
    } else {
        const int ks = blk - 32, k0 = ks * 32;
        #pragma unroll
        for (int i = 0; i < 8; ++i) {
            int j = t + i * 256;
            int k = j >> 6, n4 = (j & 63) << 2;
            *(float4*)&lds[k][n4] = *(const float4*)&W2[(size_t)(k0 + k) * HNB + n4];
        }
        __syncthreads();
        const int fl = t & 63, cg0 = t >> 6;
        const int kb = (fl >> 4) * 8;
        #pragma unroll
        for (int i = 0; i < 4; ++i) {
            const int cg = cg0 * 4 + i;
            const int col = cg * 16 + (fl & 15);
            union { _Float16 h[8]; int4 v; } H, L;
            #pragma unroll
            for (int e = 0; e < 8; ++e) {
                float v = lds[kb + e][col];
                _Float16 hh = (_Float16)v;
                H.h[e] = hh;
                L.h[e] = (_Float16)((v - (float)hh) * 4096.f);
            }
            char* d = blobs + W2BASE + ks * W2TILE + cg * 1024 + fl * 16;
            *(int4*)d = H.v;
            *(int4*)(d + 16384) = L.v;
        }
    }
}

// ---------------------------------------------------------------------------
// K1: mega (R11 body + decoupled-lookback carry propagation).
// Block = 32 rows = one chunk; 512 thr (8 waves), grid 512 -> 2 blocks/CU
// (all co-resident -> spin-wait safe). GEMM1 glds pipeline (counted vmcnt),
// GELU -> H frag-ordered -> GEMM2 (W2 L2-direct) -> z -> local scan (regs) ->
// publish carry (device-scope) -> lookback with bounded-tail early exit ->
// single out0 write; waves 4-7 fill Pi/K/R.
// ---------------------------------------------------------------------------
__global__ __launch_bounds__(512, 4) void k_mega(
    const float* __restrict__ A,      // content [16384][1024]
    const float* __restrict__ theta,  // [16384][256]
    const float* __restrict__ b1, const float* __restrict__ b2,
    const float* __restrict__ logPi, const float* __restrict__ logR,
    const char* __restrict__ blobs,
    float* __restrict__ out0, float* __restrict__ out2,
    float* fill1, float* fill3,       // non-null only in ws/lookback mode
    float* carry, int cstride,
    int* flags, int mode)             // mode 1 = lookback; 0 = fallback
{
    __shared__ __attribute__((aligned(16))) char smem[SMEMSZ];

    const int tid  = threadIdx.x;
    const int blk  = blockIdx.x;
    const int m0   = blk * CLK;
    const int lane = tid & 63;
    const int wid  = tid >> 6;
    const int ln15 = lane & 15;
    const int q    = lane >> 4;
    const int np   = wid & 3;    // col group
    const int mh   = wid >> 2;   // row half

    // ---- raw A staging (waves 0-3; wave w = region [mh_s][half_s])
    const int mh_s = wid >> 1, half_s = wid & 1;
    const float* aSrc = A + (size_t)(m0 + 16 * mh_s + ln15) * DM + q * 8 + half_s * 4;
    const int rawDst = wid * 1024 + lane * 16;

    // ---- W1 staging (waves 4-7; wave 4+wq byte-copies np-region wq)
    const int wq = wid & 3;
    const char* wSrc = blobs + wq * 2048 + (size_t)lane * 16;
    const int   wDst = wq * 2048 + lane * 16;

    v4f acc1[2], acc2[2];
    acc1[0] = acc1[1] = (v4f){0.f, 0.f, 0.f, 0.f};
    acc2[0] = acc2[1] = (v4f){0.f, 0.f, 0.f, 0.f};

#define STEP(KT, AV, WV, DO_RAW, DO_W) do { \
    if (wid < 4) { \
        if (DO_RAW) gld16(aSrc + (size_t)((KT) + 3) * 32, \
                          smem + RAWOFF + (((KT) + 3) & 3) * 4096 + rawDst); \
    } else if (DO_W) { \
        const char* ws_ = wSrc + (size_t)((KT) + 2) * W1TILE; \
        char* wd_ = smem + W1OFF + (((KT) + 2) % 3) * 16384 + wDst; \
        gld16(ws_, wd_);             gld16(ws_ + 1024, wd_ + 1024); \
        gld16(ws_ + 8192, wd_ + 8192); gld16(ws_ + 9216, wd_ + 9216); \
    } \
    { \
        const char* rawb = smem + RAWOFF + ((KT) & 3) * 4096 + mh * 2048 + lane * 16; \
        v4f lo = *(const v4f*)rawb; \
        v4f hi = *(const v4f*)(rawb + 1024); \
        const char* wbB = smem + W1OFF + ((KT) % 3) * 16384 + np * 2048 + lane * 16; \
        v8h wh0 = *(const v8h*)(wbB); \
        v8h wh1 = *(const v8h*)(wbB + 1024); \
        v8h wl0 = *(const v8h*)(wbB + 8192); \
        v8h wl1 = *(const v8h*)(wbB + 9216); \
        v8h ah, al; \
        _Pragma("unroll") \
        for (int e_ = 0; e_ < 4; ++e_) { \
            _Float16 t0_ = (_Float16)lo[e_]; \
            ah[e_] = t0_; \
            al[e_] = (_Float16)((lo[e_] - (float)t0_) * 4096.f); \
            _Float16 t1_ = (_Float16)hi[e_]; \
            ah[e_ + 4] = t1_; \
            al[e_ + 4] = (_Float16)((hi[e_] - (float)t1_) * 4096.f); \
        } \
        acc1[0] = MFMA16(ah, wh0, acc1[0]); \
        acc2[0] = MFMA16(ah, wl0, acc2[0]); \
        acc2[0] = MFMA16(al, wh0, acc2[0]); \
        acc1[1] = MFMA16(ah, wh1, acc1[1]); \
        acc2[1] = MFMA16(ah, wl1, acc2[1]); \
        acc2[1] = MFMA16(al, wh1, acc2[1]); \
    } \
    if (wid < 4) { VMCNT(AV); } else { VMCNT(WV); } \
    BARRIER(); \
} while (0)

    // ---- prologue: raw 0,1,2 -> slots 0,1,2; W 0,1 -> bufs 0,1
    if (wid < 4) {
        gld16(aSrc,      smem + RAWOFF + 0 * 4096 + rawDst);
        gld16(aSrc + 32, smem + RAWOFF + 1 * 4096 + rawDst);
        gld16(aSrc + 64, smem + RAWOFF + 2 * 4096 + rawDst);
        VMCNT(2);
    } else {
        #pragma unroll
        for (int t2 = 0; t2 < 2; ++t2) {
            const char* ws_ = wSrc + (size_t)t2 * W1TILE;
            char* wd_ = smem + W1OFF + t2 * 16384 + wDst;
            gld16(ws_, wd_);               gld16(ws_ + 1024, wd_ + 1024);
            gld16(ws_ + 8192, wd_ + 8192); gld16(ws_ + 9216, wd_ + 9216);
        }
        VMCNT(4);
    }
    BARRIER();

    STEP(0,2,4,1,1);  STEP(1,2,4,1,1);  STEP(2,2,4,1,1);  STEP(3,2,4,1,1);
    STEP(4,2,4,1,1);  STEP(5,2,4,1,1);  STEP(6,2,4,1,1);  STEP(7,2,4,1,1);
    STEP(8,2,4,1,1);  STEP(9,2,4,1,1);  STEP(10,2,4,1,1); STEP(11,2,4,1,1);
    STEP(12,2,4,1,1); STEP(13,2,4,1,1); STEP(14,2,4,1,1); STEP(15,2,4,1,1);
    STEP(16,2,4,1,1); STEP(17,2,4,1,1); STEP(18,2,4,1,1); STEP(19,2,4,1,1);
    STEP(20,2,4,1,1); STEP(21,2,4,1,1); STEP(22,2,4,1,1); STEP(23,2,4,1,1);
    STEP(24,2,4,1,1); STEP(25,2,4,1,1); STEP(26,2,4,1,1); STEP(27,2,4,1,1);
    STEP(28,2,4,1,1); STEP(29,1,4,0,1); STEP(30,0,0,0,0); STEP(31,0,0,0,0);
#undef STEP

    // ---- GELU -> H split, fragment-ordered
    const float inv = 1.f / 4096.f;
    #pragma unroll
    for (int ni = 0; ni < 2; ++ni) {
        const int colH = 32 * np + 16 * ni + ln15;
        const float bv = b1[colH];
        const int qH = (colH >> 3) & 3;
        const int eH = colH & 7;
        #pragma unroll
        for (int r = 0; r < 4; ++r) {
            float y = acc1[ni][r] + acc2[ni][r] * inv + bv;
            float h = 0.5f * y * (1.f + erff(y * 0.70710678118654752f));
            _Float16 hh = (_Float16)h;
            _Float16 hl = (_Float16)((h - (float)hh) * 4096.f);
            const int fl = (4 * q + r) + 16 * qH;
            const int byte_ = mh * 4096 + np * 1024 + fl * 16 + eH * 2;
            *(_Float16*)(smem + HHOFF + byte_) = hh;
            *(_Float16*)(smem + HLOFF + byte_) = hl;
        }
    }
    BARRIER();

    // ---- GEMM2: H frag reads lane-linear; W2 register-direct from L2
    v4f c1[4], c2[4];
    #pragma unroll
    for (int i = 0; i < 4; ++i) {
        c1[i] = (v4f){0.f, 0.f, 0.f, 0.f};
        c2[i] = (v4f){0.f, 0.f, 0.f, 0.f};
    }
    #pragma unroll
    for (int ks = 0; ks < 4; ++ks) {
        v8h hh = *(const v8h*)(smem + HHOFF + mh * 4096 + ks * 1024 + lane * 16);
        v8h hl = *(const v8h*)(smem + HLOFF + mh * 4096 + ks * 1024 + lane * 16);
        #pragma unroll
        for (int ni = 0; ni < 4; ++ni) {
            const char* wp = blobs + W2BASE + (size_t)ks * W2TILE
                           + (4 * np + ni) * 1024 + (size_t)lane * 16;
            v8h w2h = *(const v8h*)wp;
            v8h w2l = *(const v8h*)(wp + 16384);
            c1[ni] = MFMA16(hh, w2h, c1[ni]);
            c2[ni] = MFMA16(hh, w2l, c2[ni]);
            c2[ni] = MFMA16(hl, w2h, c2[ni]);
        }
    }

    // ---- z = pi*tanh(y2) -> Z LDS
    #pragma unroll
    for (int ni = 0; ni < 4; ++ni) {
        const int col = 64 * np + 16 * ni + ln15;
        const float bv = b2[col];
        #pragma unroll
        for (int r = 0; r < 4; ++r) {
            const int row = 16 * mh + 4 * q + r;
            float y2 = c1[ni][r] + c2[ni][r] * inv + bv;
            *(float*)(smem + ZOFF + row * 1040 + col * 4) =
                3.14159265358979323846f * tanhf(y2);
        }
    }
    BARRIER();

    // ---- local scan (result kept in registers) + carry publish
    float svr[CLK];
    const int c = tid & 255;
    const float Pi = expf(logPi[c]);
    const float Rr = expf(logR[c]);
    const float Kc = Pi / fmaxf(Pi + Rr, 1e-8f);
    const float alpha = 1.f - Kc;
    if (tid < 256) {
        float d = 0.f;
        float tv[2][16];
        #pragma unroll
        for (int i = 0; i < 16; ++i)
            tv[0][i] = theta[(size_t)(m0 + i) * HNB + c];
        #pragma unroll
        for (int g = 0; g < 2; ++g) {
            if (g < 1) {
                #pragma unroll
                for (int i = 0; i < 16; ++i)
                    tv[1][i] = theta[(size_t)(m0 + 16 + i) * HNB + c];
            }
            #pragma unroll
            for (int i = 0; i < 16; ++i) {
                float z = *(const float*)(smem + ZOFF + (g * 16 + i) * 1040 + c * 4);
                float diff = z - tv[g][i];
                float kq = rintf(diff * 0.15915494309189533577f);
                float nu = (float)((double)diff - (double)kq * 6.283185307179586476925286766559);
                d = fmaf(alpha, d, Kc * nu);
                svr[g * 16 + i] = tv[g][i] + d;
            }
        }
        if (mode)
            __hip_atomic_store(&carry[(size_t)blk * cstride + c], d,
                               __ATOMIC_RELAXED, __HIP_MEMORY_SCOPE_AGENT);
        else
            carry[(size_t)blk * cstride + c] = d;
    }
    __syncthreads();
    if (mode && tid == 0)
        __hip_atomic_store(&flags[blk], 1, __ATOMIC_RELEASE,
                           __HIP_MEMORY_SCOPE_AGENT);

    // ---- lookback + out0 write (waves 0-3); fills (waves 4-7)
    if (tid < 256) {
        if (mode) {
            float A32 = alpha;
            #pragma unroll
            for (int i = 0; i < 5; ++i) A32 *= A32;   // alpha^32
            const int s  = blk & (CPB - 1);
            const int bb = blk - s;
            float D = 0.f, w = 1.f;
            for (int j = s - 1; j >= 0; --j) {
                while (__hip_atomic_load(&flags[bb + j], __ATOMIC_ACQUIRE,
                                         __HIP_MEMORY_SCOPE_AGENT) == 0) {}
                float cj = __hip_atomic_load(
                    &carry[(size_t)(bb + j) * cstride + c],
                    __ATOMIC_RELAXED, __HIP_MEMORY_SCOPE_AGENT);
                D = fmaf(w, cj, D);
                w *= A32;
                // |carry| <= pi, so remaining tail < w*pi/(1-A32): negligible
                if (__all(w < 1e-10f)) break;
            }
            float wo = alpha * D;
            #pragma unroll
            for (int i = 0; i < CLK; ++i) {
                out0[(size_t)(m0 + i) * HNB + c] = svr[i] + wo;
                wo *= alpha;
            }
        } else {
            #pragma unroll
            for (int i = 0; i < CLK; ++i)
                out0[(size_t)(m0 + i) * HNB + c] = svr[i];
        }
    } else {
        if (fill1) {
            #pragma unroll 4
            for (int i = 0; i < CLK; ++i) {
                size_t idx = (size_t)(m0 + i) * HNB + c;
                out2[idx]  = Kc;
                fill1[idx] = Pi;
                fill3[idx] = Rr;
            }
        } else {
            #pragma unroll 4
            for (int i = 0; i < CLK; ++i)
                out2[(size_t)(m0 + i) * HNB + c] = Kc;
        }
    }
}

// ---------------------------------------------------------------------------
// Fallback K2: exclusive scan of chunk carries (alpha^32), one block/batch.
// ---------------------------------------------------------------------------
__global__ __launch_bounds__(256) void k_cscan(
    const float* __restrict__ logPi, const float* __restrict__ logR,
    float* carry, int cstride)
{
    const int c = threadIdx.x, b = blockIdx.x;
    const float Pi = expf(logPi[c]);
    const float Rr = expf(logR[c]);
    const float alpha = 1.f - Pi / fmaxf(Pi + Rr, 1e-8f);
    float A32 = alpha;
    #pragma unroll
    for (int i = 0; i < 5; ++i) A32 *= A32;
    float D = 0.f;
    for (int s0 = 0; s0 < CPB; s0 += 16) {
        float a[16];
        #pragma unroll
        for (int j = 0; j < 16; ++j)
            a[j] = carry[(size_t)(b * CPB + s0 + j) * cstride + c];
        #pragma unroll
        for (int j = 0; j < 16; ++j) {
            carry[(size_t)(b * CPB + s0 + j) * cstride + c] = D;
            D = fmaf(A32, D, a[j]);
        }
    }
}

// ---------------------------------------------------------------------------
// Fallback K3: out0 += alpha^(i+1)*D; also fills Pi/R.
// ---------------------------------------------------------------------------
__global__ __launch_bounds__(256) void k_apply(
    const float* __restrict__ logPi, const float* __restrict__ logR,
    float* __restrict__ out0, float* out1, float* out3,
    const float* carry, int cstride)
{
    const int blk = blockIdx.x;
    const int c = threadIdx.x;
    const float Pi = expf(logPi[c]);
    const float Rr = expf(logR[c]);
    const float Kc = Pi / fmaxf(Pi + Rr, 1e-8f);
    const float alpha = 1.f - Kc;
    float D = carry[(size_t)blk * cstride + c];
    float w = alpha * D;
    const size_t base = (size_t)blk * (CLK * HNB) + c;
    #pragma unroll 4
    for (int i = 0; i < CLK; ++i) {
        size_t idx = base + (size_t)i * HNB;
        out0[idx] += w;
        out1[idx] = Pi;
        out3[idx] = Rr;
        w *= alpha;
    }
}

extern "C" void kernel_launch(void* const* d_in, const int* in_sizes, int n_in,
                              void* d_out, int out_size, void* d_ws, size_t ws_size,
                              hipStream_t stream) {
    const float* theta   = (const float*)d_in[0];
    const float* content = (const float*)d_in[1];
    const float* W1      = (const float*)d_in[2];
    const float* b1      = (const float*)d_in[3];
    const float* W2      = (const float*)d_in[4];
    const float* b2      = (const float*)d_in[5];
    const float* logPi   = (const float*)d_in[6];
    const float* logR    = (const float*)d_in[7];

    float* out  = (float*)d_out;
    float* out0 = out;
    float* out1 = out + (size_t)MTOT * HNB;
    float* out2 = out + (size_t)2 * MTOT * HNB;
    float* out3 = out + (size_t)3 * MTOT * HNB;

    const size_t flag_bytes  = (size_t)NBLK * 4;                // 2 KB
    const size_t carry_bytes = (size_t)NBLK * 256 * 4;          // 512 KB
    const size_t need = flag_bytes + carry_bytes + BLOB_BYTES;  // ~1.34 MB

    if (ws_size >= need) {
        // ---- lookback mode: 2 launches, no RMW pass ----
        int*   flags = (int*)d_ws;
        float* carry = (float*)((char*)d_ws + flag_bytes);
        char*  blobs = (char*)d_ws + flag_bytes + carry_bytes;
        hipLaunchKernelGGL(k_prep, dim3(36), dim3(256), 0, stream,
                           W1, W2, blobs, flags);
        hipLaunchKernelGGL(k_mega, dim3(NBLK), dim3(512), 0, stream,
                           content, theta, b1, b2, logPi, logR, blobs,
                           out0, out2, out1, out3, carry, 256, flags, 1);
    } else {
        // ---- fallback: 4 launches, carries in out3, blobs in out1 ----
        float* carry = out3;
        int cstride  = CLK * HNB;       // 8192 (chunk's own out3 rows)
        char* blobs  = (char*)out1;
        hipLaunchKernelGGL(k_prep, dim3(36), dim3(256), 0, stream,
                           W1, W2, blobs, (int*)nullptr);
        hipLaunchKernelGGL(k_mega, dim3(NBLK), dim3(512), 0, stream,
                           content, theta, b1, b2, logPi, logR, blobs,
                           out0, out2, (float*)nullptr, (float*)nullptr,
                           carry, cstride, (int*)nullptr, 0);
        hipLaunchKernelGGL(k_cscan, dim3(NBAT), dim3(256), 0, stream,
                           logPi, logR, carry, cstride);
        hipLaunchKernelGGL(k_apply, dim3(NBLK), dim3(256), 0, stream,
                           logPi, logR, out0, out1, out3, carry, cstride);
    }
}

// Round 15
// 101.792 us; speedup vs baseline: 1.0042x; 1.0042x over previous
//
#include <hip/hip_runtime.h>
#include <math.h>

// Problem geometry
#define MTOT  16384      // B*L
#define DM    1024
#define HIDN  128
#define HNB   256
#define NBAT  4
#define CLK   32         // rows per k_mega block == scan chunk
#define NBLK  512        // MTOT/CLK -> exactly 2 blocks/CU (all co-resident)
#define CPB   128        // chunks per batch (4096/32)

typedef _Float16 v8h __attribute__((ext_vector_type(8)));
typedef float    v4f __attribute__((ext_vector_type(4)));
#define MFMA16(a,b,c) __builtin_amdgcn_mfma_f32_16x16x32_f16((a),(b),(c),0,0,0)

// FRAGMENT-ORDERED weight blobs (d_ws when big enough, else out1 region):
//  W1: 32 k-tiles x 16384 B. Tile: h-frags [np 0..3][fi 0..1][64 lanes x 16B]
//      then l-frags at +8192. Entry lane l: col=32np+16fi+(l&15),
//      k = kt*32 + (l>>4)*8 + e.
//  W2 @524288: 4 k-tiles x 32768 B: h [cg 0..15][64 x 16B], l at +16384.
#define W1TILE  16384
#define W2BASE  524288
#define W2TILE  32768
#define BLOB_BYTES 655360

// k_mega LDS map (65536 B -> 2 blocks/CU):
//  GEMM1: raw A fp32 ring 4 x 4096 @0 ; W1 tri-buffer 3 x 16384 @16384
//  H (post-GEMM1): Hh 8KB @0 | Hl 8KB @8192     (raw dead)
//  Z (post-GEMM2): [32][260] f32 @16384 (33280) (W1 dead); scan result S
//  overwrites Z in-place (same thread, no barrier needed)
#define RAWOFF 0
#define W1OFF  16384
#define HHOFF  0
#define HLOFF  8192
#define ZOFF   16384
#define SMEMSZ 65536

#define VMCNT_(N) asm volatile("s_waitcnt vmcnt(" #N ")" ::: "memory")
#define VMCNT(N) VMCNT_(N)
#define BARRIER() do { asm volatile("s_waitcnt lgkmcnt(0)" ::: "memory"); \
                       __builtin_amdgcn_s_barrier(); } while (0)

typedef const __attribute__((address_space(1))) void* gas1_t;
typedef __attribute__((address_space(3))) void* las3_t;

__device__ __forceinline__ void gld16(const void* g, void* l) {
    __builtin_amdgcn_global_load_lds((gas1_t)g, (las3_t)l, 16, 0, 0);
}

// ---------------------------------------------------------------------------
// K0: weights -> fp16-split fragment-ordered blobs; zero lookback flags.
//     Xh = fp16(x); Xl = fp16((x - Xh) * 4096)
// ---------------------------------------------------------------------------
__global__ __launch_bounds__(256) void k_prep(
    const float* __restrict__ W1,   // [1024][128]
    const float* __restrict__ W2,   // [128][256]
    char* __restrict__ blobs,
    int* flags)                     // null in fallback mode
{
    __shared__ float lds[32][260];
    const int t = threadIdx.x, blk = blockIdx.x;
    if (flags && blk < 2)
        __hip_atomic_store(&flags[blk * 256 + t], 0, __ATOMIC_RELAXED,
                           __HIP_MEMORY_SCOPE_AGENT);
    if (blk < 32) {
        const int k0 = blk * 32;
        #pragma unroll
        for (int i = 0; i < 4; ++i) {
            int j = t + i * 256;
            int k = j >> 5, n4 = (j & 31) << 2;
            *(float4*)&lds[k][n4] = *(const float4*)&W1[(size_t)(k0 + k) * HIDN + n4];
        }
        __syncthreads();
        const int fl = t & 63, np = t >> 6;
        const int kb = (fl >> 4) * 8;
        #pragma unroll
        for (int fi = 0; fi < 2; ++fi) {
            const int col = 32 * np + 16 * fi + (fl & 15);
            union { _Float16 h[8]; int4 v; } H, L;
            #pragma unroll
            for (int e = 0; e < 8; ++e) {
                float v = lds[kb + e][col];
                _Float16 hh = (_Float16)v;
                H.h[e] = hh;
                L.h[e] = (_Float16)((v - (float)hh) * 4096.f);
            }
            char* d = blobs + blk * W1TILE + np * 2048 + fi * 1024 + fl * 16;
            *(int4*)d = H.v;
            *(int4*)(d + 8192) = L.v;
        }
    } else {
        const int ks = blk - 32, k0 = ks * 32;
        #pragma unroll
        for (int i = 0; i < 8; ++i) {
            int j = t + i * 256;
            int k = j >> 6, n4 = (j & 63) << 2;
            *(float4*)&lds[k][n4] = *(const float4*)&W2[(size_t)(k0 + k) * HNB + n4];
        }
        __syncthreads();
        const int fl = t & 63, cg0 = t >> 6;
        const int kb = (fl >> 4) * 8;
        #pragma unroll
        for (int i = 0; i < 4; ++i) {
            const int cg = cg0 * 4 + i;
            const int col = cg * 16 + (fl & 15);
            union { _Float16 h[8]; int4 v; } H, L;
            #pragma unroll
            for (int e = 0; e < 8; ++e) {
                float v = lds[kb + e][col];
                _Float16 hh = (_Float16)v;
                H.h[e] = hh;
                L.h[e] = (_Float16)((v - (float)hh) * 4096.f);
            }
            char* d = blobs + W2BASE + ks * W2TILE + cg * 1024 + fl * 16;
            *(int4*)d = H.v;
            *(int4*)(d + 16384) = L.v;
        }
    }
}

// ---------------------------------------------------------------------------
// K1: mega (R11 body + decoupled lookback, spill-free and low-traffic):
//  - scan result kept in LDS (in-place over Z), not registers
//  - flag polling by wave leader only (64x less atomic traffic)
// Block = 32 rows = one chunk; 512 thr (8 waves), grid 512 -> 2 blocks/CU
// co-resident (spin-safe). Single out0 write; waves 4-7 fill Pi/K/R.
// ---------------------------------------------------------------------------
__global__ __launch_bounds__(512, 4) void k_mega(
    const float* __restrict__ A,      // content [16384][1024]
    const float* __restrict__ theta,  // [16384][256]
    const float* __restrict__ b1, const float* __restrict__ b2,
    const float* __restrict__ logPi, const float* __restrict__ logR,
    const char* __restrict__ blobs,
    float* __restrict__ out0, float* __restrict__ out2,
    float* fill1, float* fill3,       // non-null only in lookback mode
    float* carry, int cstride,
    int* flags, int mode)             // mode 1 = lookback; 0 = fallback
{
    __shared__ __attribute__((aligned(16))) char smem[SMEMSZ];

    const int tid  = threadIdx.x;
    const int blk  = blockIdx.x;
    const int m0   = blk * CLK;
    const int lane = tid & 63;
    const int wid  = tid >> 6;
    const int ln15 = lane & 15;
    const int q    = lane >> 4;
    const int np   = wid & 3;    // col group
    const int mh   = wid >> 2;   // row half

    // ---- raw A staging (waves 0-3; wave w = region [mh_s][half_s])
    const int mh_s = wid >> 1, half_s = wid & 1;
    const float* aSrc = A + (size_t)(m0 + 16 * mh_s + ln15) * DM + q * 8 + half_s * 4;
    const int rawDst = wid * 1024 + lane * 16;

    // ---- W1 staging (waves 4-7; wave 4+wq byte-copies np-region wq)
    const int wq = wid & 3;
    const char* wSrc = blobs + wq * 2048 + (size_t)lane * 16;
    const int   wDst = wq * 2048 + lane * 16;

    v4f acc1[2], acc2[2];
    acc1[0] = acc1[1] = (v4f){0.f, 0.f, 0.f, 0.f};
    acc2[0] = acc2[1] = (v4f){0.f, 0.f, 0.f, 0.f};

#define STEP(KT, AV, WV, DO_RAW, DO_W) do { \
    if (wid < 4) { \
        if (DO_RAW) gld16(aSrc + (size_t)((KT) + 3) * 32, \
                          smem + RAWOFF + (((KT) + 3) & 3) * 4096 + rawDst); \
    } else if (DO_W) { \
        const char* ws_ = wSrc + (size_t)((KT) + 2) * W1TILE; \
        char* wd_ = smem + W1OFF + (((KT) + 2) % 3) * 16384 + wDst; \
        gld16(ws_, wd_);             gld16(ws_ + 1024, wd_ + 1024); \
        gld16(ws_ + 8192, wd_ + 8192); gld16(ws_ + 9216, wd_ + 9216); \
    } \
    { \
        const char* rawb = smem + RAWOFF + ((KT) & 3) * 4096 + mh * 2048 + lane * 16; \
        v4f lo = *(const v4f*)rawb; \
        v4f hi = *(const v4f*)(rawb + 1024); \
        const char* wbB = smem + W1OFF + ((KT) % 3) * 16384 + np * 2048 + lane * 16; \
        v8h wh0 = *(const v8h*)(wbB); \
        v8h wh1 = *(const v8h*)(wbB + 1024); \
        v8h wl0 = *(const v8h*)(wbB + 8192); \
        v8h wl1 = *(const v8h*)(wbB + 9216); \
        v8h ah, al; \
        _Pragma("unroll") \
        for (int e_ = 0; e_ < 4; ++e_) { \
            _Float16 t0_ = (_Float16)lo[e_]; \
            ah[e_] = t0_; \
            al[e_] = (_Float16)((lo[e_] - (float)t0_) * 4096.f); \
            _Float16 t1_ = (_Float16)hi[e_]; \
            ah[e_ + 4] = t1_; \
            al[e_ + 4] = (_Float16)((hi[e_] - (float)t1_) * 4096.f); \
        } \
        acc1[0] = MFMA16(ah, wh0, acc1[0]); \
        acc2[0] = MFMA16(ah, wl0, acc2[0]); \
        acc2[0] = MFMA16(al, wh0, acc2[0]); \
        acc1[1] = MFMA16(ah, wh1, acc1[1]); \
        acc2[1] = MFMA16(ah, wl1, acc2[1]); \
        acc2[1] = MFMA16(al, wh1, acc2[1]); \
    } \
    if (wid < 4) { VMCNT(AV); } else { VMCNT(WV); } \
    BARRIER(); \
} while (0)

    // ---- prologue: raw 0,1,2 -> slots 0,1,2; W 0,1 -> bufs 0,1
    if (wid < 4) {
        gld16(aSrc,      smem + RAWOFF + 0 * 4096 + rawDst);
        gld16(aSrc + 32, smem + RAWOFF + 1 * 4096 + rawDst);
        gld16(aSrc + 64, smem + RAWOFF + 2 * 4096 + rawDst);
        VMCNT(2);
    } else {
        #pragma unroll
        for (int t2 = 0; t2 < 2; ++t2) {
            const char* ws_ = wSrc + (size_t)t2 * W1TILE;
            char* wd_ = smem + W1OFF + t2 * 16384 + wDst;
            gld16(ws_, wd_);               gld16(ws_ + 1024, wd_ + 1024);
            gld16(ws_ + 8192, wd_ + 8192); gld16(ws_ + 9216, wd_ + 9216);
        }
        VMCNT(4);
    }
    BARRIER();

    STEP(0,2,4,1,1);  STEP(1,2,4,1,1);  STEP(2,2,4,1,1);  STEP(3,2,4,1,1);
    STEP(4,2,4,1,1);  STEP(5,2,4,1,1);  STEP(6,2,4,1,1);  STEP(7,2,4,1,1);
    STEP(8,2,4,1,1);  STEP(9,2,4,1,1);  STEP(10,2,4,1,1); STEP(11,2,4,1,1);
    STEP(12,2,4,1,1); STEP(13,2,4,1,1); STEP(14,2,4,1,1); STEP(15,2,4,1,1);
    STEP(16,2,4,1,1); STEP(17,2,4,1,1); STEP(18,2,4,1,1); STEP(19,2,4,1,1);
    STEP(20,2,4,1,1); STEP(21,2,4,1,1); STEP(22,2,4,1,1); STEP(23,2,4,1,1);
    STEP(24,2,4,1,1); STEP(25,2,4,1,1); STEP(26,2,4,1,1); STEP(27,2,4,1,1);
    STEP(28,2,4,1,1); STEP(29,1,4,0,1); STEP(30,0,0,0,0); STEP(31,0,0,0,0);
#undef STEP

    // ---- GELU -> H split, fragment-ordered
    const float inv = 1.f / 4096.f;
    #pragma unroll
    for (int ni = 0; ni < 2; ++ni) {
        const int colH = 32 * np + 16 * ni + ln15;
        const float bv = b1[colH];
        const int qH = (colH >> 3) & 3;
        const int eH = colH & 7;
        #pragma unroll
        for (int r = 0; r < 4; ++r) {
            float y = acc1[ni][r] + acc2[ni][r] * inv + bv;
            float h = 0.5f * y * (1.f + erff(y * 0.70710678118654752f));
            _Float16 hh = (_Float16)h;
            _Float16 hl = (_Float16)((h - (float)hh) * 4096.f);
            const int fl = (4 * q + r) + 16 * qH;
            const int byte_ = mh * 4096 + np * 1024 + fl * 16 + eH * 2;
            *(_Float16*)(smem + HHOFF + byte_) = hh;
            *(_Float16*)(smem + HLOFF + byte_) = hl;
        }
    }
    BARRIER();

    // ---- GEMM2: H frag reads lane-linear; W2 register-direct from L2
    v4f c1[4], c2[4];
    #pragma unroll
    for (int i = 0; i < 4; ++i) {
        c1[i] = (v4f){0.f, 0.f, 0.f, 0.f};
        c2[i] = (v4f){0.f, 0.f, 0.f, 0.f};
    }
    #pragma unroll
    for (int ks = 0; ks < 4; ++ks) {
        v8h hh = *(const v8h*)(smem + HHOFF + mh * 4096 + ks * 1024 + lane * 16);
        v8h hl = *(const v8h*)(smem + HLOFF + mh * 4096 + ks * 1024 + lane * 16);
        #pragma unroll
        for (int ni = 0; ni < 4; ++ni) {
            const char* wp = blobs + W2BASE + (size_t)ks * W2TILE
                           + (4 * np + ni) * 1024 + (size_t)lane * 16;
            v8h w2h = *(const v8h*)wp;
            v8h w2l = *(const v8h*)(wp + 16384);
            c1[ni] = MFMA16(hh, w2h, c1[ni]);
            c2[ni] = MFMA16(hh, w2l, c2[ni]);
            c2[ni] = MFMA16(hl, w2h, c2[ni]);
        }
    }

    // ---- z = pi*tanh(y2) -> Z LDS
    #pragma unroll
    for (int ni = 0; ni < 4; ++ni) {
        const int col = 64 * np + 16 * ni + ln15;
        const float bv = b2[col];
        #pragma unroll
        for (int r = 0; r < 4; ++r) {
            const int row = 16 * mh + 4 * q + r;
            float y2 = c1[ni][r] + c2[ni][r] * inv + bv;
            *(float*)(smem + ZOFF + row * 1040 + col * 4) =
                3.14159265358979323846f * tanhf(y2);
        }
    }
    BARRIER();

    // ---- local scan; S overwrites Z in-place (same thread, no barrier);
    //      publish carry
    const int c = tid & 255;
    const float Pi = expf(logPi[c]);
    const float Rr = expf(logR[c]);
    const float Kc = Pi / fmaxf(Pi + Rr, 1e-8f);
    const float alpha = 1.f - Kc;
    if (tid < 256) {
        float d = 0.f;
        float tv[2][16];
        #pragma unroll
        for (int i = 0; i < 16; ++i)
            tv[0][i] = theta[(size_t)(m0 + i) * HNB + c];
        #pragma unroll
        for (int g = 0; g < 2; ++g) {
            if (g < 1) {
                #pragma unroll
                for (int i = 0; i < 16; ++i)
                    tv[1][i] = theta[(size_t)(m0 + 16 + i) * HNB + c];
            }
            #pragma unroll
            for (int i = 0; i < 16; ++i) {
                char* zp = smem + ZOFF + (g * 16 + i) * 1040 + c * 4;
                float z = *(const float*)zp;
                float diff = z - tv[g][i];
                float kq = rintf(diff * 0.15915494309189533577f);
                float nu = (float)((double)diff - (double)kq * 6.283185307179586476925286766559);
                d = fmaf(alpha, d, Kc * nu);
                *(float*)zp = tv[g][i] + d;     // S value, read back later
            }
        }
        if (mode)
            __hip_atomic_store(&carry[(size_t)blk * cstride + c], d,
                               __ATOMIC_RELAXED, __HIP_MEMORY_SCOPE_AGENT);
        else
            carry[(size_t)blk * cstride + c] = d;
    }
    __syncthreads();
    if (mode && tid == 0)
        __hip_atomic_store(&flags[blk], 1, __ATOMIC_RELEASE,
                           __HIP_MEMORY_SCOPE_AGENT);

    // ---- lookback + out0 write (waves 0-3); fills (waves 4-7)
    if (tid < 256) {
        float wo = 0.f;
        if (mode) {
            float A32 = alpha;
            #pragma unroll
            for (int i = 0; i < 5; ++i) A32 *= A32;   // alpha^32
            const int s  = blk & (CPB - 1);
            const int bb = blk - s;
            float D = 0.f, w = 1.f;
            for (int j = s - 1; j >= 0; --j) {
                // wave-leader poll: only lane 0 issues atomics, broadcast
                int f;
                do {
                    f = 0;
                    if (lane == 0)
                        f = __hip_atomic_load(&flags[bb + j], __ATOMIC_ACQUIRE,
                                              __HIP_MEMORY_SCOPE_AGENT);
                    f = __shfl(f, 0);
                } while (f == 0);
                float cj = __hip_atomic_load(
                    &carry[(size_t)(bb + j) * cstride + c],
                    __ATOMIC_RELAXED, __HIP_MEMORY_SCOPE_AGENT);
                D = fmaf(w, cj, D);
                w *= A32;
                // |carry| <= pi -> remaining tail < w*pi: below fp32 ulp
                if (__all(w < 1e-10f)) break;
            }
            wo = alpha * D;
        }
        #pragma unroll
        for (int i = 0; i < CLK; ++i) {
            float sv = *(const float*)(smem + ZOFF + i * 1040 + c * 4);
            out0[(size_t)(m0 + i) * HNB + c] = sv + wo;
            wo *= alpha;
        }
    } else {
        if (fill1) {
            #pragma unroll 4
            for (int i = 0; i < CLK; ++i) {
                size_t idx = (size_t)(m0 + i) * HNB + c;
                out2[idx]  = Kc;
                fill1[idx] = Pi;
                fill3[idx] = Rr;
            }
        } else {
            #pragma unroll 4
            for (int i = 0; i < CLK; ++i)
                out2[(size_t)(m0 + i) * HNB + c] = Kc;
        }
    }
}

// ---------------------------------------------------------------------------
// Fallback K2: exclusive scan of chunk carries (alpha^32), one block/batch.
// ---------------------------------------------------------------------------
__global__ __launch_bounds__(256) void k_cscan(
    const float* __restrict__ logPi, const float* __restrict__ logR,
    float* carry, int cstride)
{
    const int c = threadIdx.x, b = blockIdx.x;
    const float Pi = expf(logPi[c]);
    const float Rr = expf(logR[c]);
    const float alpha = 1.f - Pi / fmaxf(Pi + Rr, 1e-8f);
    float A32 = alpha;
    #pragma unroll
    for (int i = 0; i < 5; ++i) A32 *= A32;
    float D = 0.f;
    for (int s0 = 0; s0 < CPB; s0 += 16) {
        float a[16];
        #pragma unroll
        for (int j = 0; j < 16; ++j)
            a[j] = carry[(size_t)(b * CPB + s0 + j) * cstride + c];
        #pragma unroll
        for (int j = 0; j < 16; ++j) {
            carry[(size_t)(b * CPB + s0 + j) * cstride + c] = D;
            D = fmaf(A32, D, a[j]);
        }
    }
}

// ---------------------------------------------------------------------------
// Fallback K3: out0 += alpha^(i+1)*D; also fills Pi/R.
// ---------------------------------------------------------------------------
__global__ __launch_bounds__(256) void k_apply(
    const float* __restrict__ logPi, const float* __restrict__ logR,
    float* __restrict__ out0, float* out1, float* out3,
    const float* carry, int cstride)
{
    const int blk = blockIdx.x;
    const int c = threadIdx.x;
    const float Pi = expf(logPi[c]);
    const float Rr = expf(logR[c]);
    const float Kc = Pi / fmaxf(Pi + Rr, 1e-8f);
    const float alpha = 1.f - Kc;
    float D = carry[(size_t)blk * cstride + c];
    float w = alpha * D;
    const size_t base = (size_t)blk * (CLK * HNB) + c;
    #pragma unroll 4
    for (int i = 0; i < CLK; ++i) {
        size_t idx = base + (size_t)i * HNB;
        out0[idx] += w;
        out1[idx] = Pi;
        out3[idx] = Rr;
        w *= alpha;
    }
}

extern "C" void kernel_launch(void* const* d_in, const int* in_sizes, int n_in,
                              void* d_out, int out_size, void* d_ws, size_t ws_size,
                              hipStream_t stream) {
    const float* theta   = (const float*)d_in[0];
    const float* content = (const float*)d_in[1];
    const float* W1      = (const float*)d_in[2];
    const float* b1      = (const float*)d_in[3];
    const float* W2      = (const float*)d_in[4];
    const float* b2      = (const float*)d_in[5];
    const float* logPi   = (const float*)d_in[6];
    const float* logR    = (const float*)d_in[7];

    float* out  = (float*)d_out;
    float* out0 = out;
    float* out1 = out + (size_t)MTOT * HNB;
    float* out2 = out + (size_t)2 * MTOT * HNB;
    float* out3 = out + (size_t)3 * MTOT * HNB;

    const size_t flag_bytes  = (size_t)NBLK * 4;                // 2 KB
    const size_t carry_bytes = (size_t)NBLK * 256 * 4;          // 512 KB
    const size_t need = flag_bytes + carry_bytes + BLOB_BYTES;  // ~1.34 MB

    if (ws_size >= need) {
        // ---- lookback mode: 2 launches, no RMW pass ----
        int*   flags = (int*)d_ws;
        float* carry = (float*)((char*)d_ws + flag_bytes);
        char*  blobs = (char*)d_ws + flag_bytes + carry_bytes;
        hipLaunchKernelGGL(k_prep, dim3(36), dim3(256), 0, stream,
                           W1, W2, blobs, flags);
        hipLaunchKernelGGL(k_mega, dim3(NBLK), dim3(512), 0, stream,
                           content, theta, b1, b2, logPi, logR, blobs,
                           out0, out2, out1, out3, carry, 256, flags, 1);
    } else {
        // ---- fallback: 4 launches, carries in out3, blobs in out1 ----
        float* carry = out3;
        int cstride  = CLK * HNB;       // 8192 (chunk's own out3 rows)
        char* blobs  = (char*)out1;
        hipLaunchKernelGGL(k_prep, dim3(36), dim3(256), 0, stream,
                           W1, W2, blobs, (int*)nullptr);
        hipLaunchKernelGGL(k_mega, dim3(NBLK), dim3(512), 0, stream,
                           content, theta, b1, b2, logPi, logR, blobs,
                           out0, out2, (float*)nullptr, (float*)nullptr,
                           carry, cstride, (int*)nullptr, 0);
        hipLaunchKernelGGL(k_cscan, dim3(NBAT), dim3(256), 0, stream,
                           logPi, logR, carry, cstride);
        hipLaunchKernelGGL(k_apply, dim3(NBLK), dim3(256), 0, stream,
                           logPi, logR, out0, out1, out3, carry, cstride);
    }
}